// Round 3
// baseline (355.056 us; speedup 1.0000x reference)
//
#include <hip/hip_runtime.h>

// ---------------------------------------------------------------------------
// 3-layer GCN: h = relu(Agg(x@W1)+b1); h = relu(Agg(h@W2)+b2); out = Agg(h@W3)+b3
// Factorized: tmp[n] = dinv[n]*(h[n]@W);  agg[i] = dinv[i]*(tmp[i] + sum tmp[src]) + b
// All fp32: max|ref| ~ 488 with threshold 5.2e-3 (1e-5 relative) forbids bf16.
// GEMM v3: A via global_load_lds w/ XOR chunk swizzle, W chunk LDS, 2-phase dbuf.
// ---------------------------------------------------------------------------

// ---------------- CSR build ----------------

__global__ __launch_bounds__(256) void count_kernel(const int* __restrict__ dst,
                                                    int* __restrict__ cnt, int E) {
    int e = blockIdx.x * 256 + threadIdx.x;
    if (e < E) atomicAdd(&cnt[dst[e]], 1);
}

__global__ __launch_bounds__(256) void dinv_kernel(const int* __restrict__ cnt,
                                                   float* __restrict__ dinv, int M) {
    int i = blockIdx.x * 256 + threadIdx.x;
    if (i < M) dinv[i] = 1.0f / sqrtf((float)cnt[i] + 1.0f);  // +1: self-loop
}

__global__ __launch_bounds__(256) void scan1_kernel(const int* __restrict__ cnt,
                                                    int* __restrict__ loc,
                                                    int* __restrict__ bsum, int M) {
    __shared__ int sm[256];
    int t = threadIdx.x;
    int i = blockIdx.x * 256 + t;
    int v = (i < M) ? cnt[i] : 0;
    sm[t] = v;
    __syncthreads();
    for (int o = 1; o < 256; o <<= 1) {
        int add = (t >= o) ? sm[t - o] : 0;
        __syncthreads();
        sm[t] += add;
        __syncthreads();
    }
    if (i < M) loc[i] = sm[t] - v;
    if (t == 255) bsum[blockIdx.x] = sm[255];
}

__global__ __launch_bounds__(256) void scan2_kernel(int* __restrict__ bsum, int NB) {
    __shared__ int sm[256];
    int t = threadIdx.x;
    int v = (t < NB) ? bsum[t] : 0;
    sm[t] = v;
    __syncthreads();
    for (int o = 1; o < 256; o <<= 1) {
        int add = (t >= o) ? sm[t - o] : 0;
        __syncthreads();
        sm[t] += add;
        __syncthreads();
    }
    if (t < NB) bsum[t] = sm[t] - v;
}

__global__ __launch_bounds__(256) void place_kernel(const int* __restrict__ src,
                                                    const int* __restrict__ dst,
                                                    const int* __restrict__ loc,
                                                    const int* __restrict__ base,
                                                    int* __restrict__ fill,
                                                    int* __restrict__ srcs, int E) {
    int e = blockIdx.x * 256 + threadIdx.x;
    if (e >= E) return;
    int d = dst[e];
    int pos = loc[d] + base[d >> 8] + atomicAdd(&fill[d], 1);
    srcs[pos] = src[e];
}

// ---------------- GEMM v3: out[m][c] = dinv[m] * sum_k A[m][k] * W[k][c] ----------------
// Block: 64 rows x C cols, 256 threads (ty=t&15 row-group, tx=t>>4 col-group).
// Thread: 4 rows (stride 16) x RN cols. KB=32 k-chunk, double-buffered.
// A tile [64][32] staged by global_load_lds with chunk'=chunk^(row&7) swizzle
// (applied on the global source AND the ds_read index -> 2-way banks only).

__device__ __forceinline__ void gload_lds16(const float* g, float* l) {
    __builtin_amdgcn_global_load_lds((const __attribute__((address_space(1))) void*)g,
                                     (__attribute__((address_space(3))) void*)l,
                                     16, 0, 0);
}

template <int K, int C, int RN>
__global__ __launch_bounds__(256) void gemm_v3(const float* __restrict__ A,
                                               const float* __restrict__ W,
                                               const float* __restrict__ dinv,
                                               float* __restrict__ out, int M) {
    constexpr int KB = 32;            // k-chunk
    constexpr int TM = 64;            // rows per block
    constexpr int RM = 4;             // rows per thread (stride 16)
    constexpr int NCH = K / KB;       // chunks
    constexpr int WR = (KB * C / 4) / 256;   // W stage rounds (float4 lanes)
    static_assert(C == 16 * RN, "col tiling");

    __shared__ __align__(16) float Ab[2][TM * KB];
    __shared__ __align__(16) float Wb[2][KB * C];

    const int t = threadIdx.x;
    const int tx = t >> 4;            // 0..15 col group
    const int ty = t & 15;            // 0..15 row group
    const int row0 = blockIdx.x * TM;

    auto stage = [&](int ch, int buf) {
        const int k0 = ch * KB;
        // A tile: 64 rows x 8 float4-chunks = 512 lanes -> 2 rounds
#pragma unroll
        for (int rnd = 0; rnd < 2; ++rnd) {
            int L = rnd * 256 + t;
            int r = L >> 3;
            int cp = L & 7;                 // LDS chunk index
            int gc = cp ^ (r & 7);          // global chunk (inverse swizzle)
            int grow = row0 + r;
            if (grow >= M) grow = M - 1;    // clamp: garbage rows never stored
            gload_lds16(A + (size_t)grow * K + k0 + gc * 4, &Ab[buf][L * 4]);
        }
        // W chunk: rows k0..k0+31 full width -> contiguous, linear copy
#pragma unroll
        for (int rnd = 0; rnd < WR; ++rnd) {
            int L = rnd * 256 + t;
            gload_lds16(W + (size_t)k0 * C + L * 4, &Wb[buf][L * 4]);
        }
    };

    float acc[RM][RN];
#pragma unroll
    for (int i = 0; i < RM; ++i)
#pragma unroll
        for (int j = 0; j < RN; ++j) acc[i][j] = 0.f;

    stage(0, 0);
    __syncthreads();

    for (int ch = 0; ch < NCH; ++ch) {
        if (ch + 1 < NCH) stage(ch + 1, (ch + 1) & 1);   // prefetch next chunk
        const float* Abuf = Ab[ch & 1];
        const float* Wbuf = Wb[ch & 1];
        for (int kq = 0; kq < KB / 4; ++kq) {
            float4 a[RM];
#pragma unroll
            for (int i = 0; i < RM; ++i) {
                int r = ty + i * 16;
                a[i] = *(const float4*)&Abuf[r * KB + ((kq ^ (r & 7)) << 2)];
            }
#pragma unroll
            for (int kk = 0; kk < 4; ++kk) {
#pragma unroll
                for (int jh = 0; jh < RN / 4; ++jh) {
                    float4 w = *(const float4*)&Wbuf[(kq * 4 + kk) * C + tx * RN + jh * 4];
#pragma unroll
                    for (int i = 0; i < RM; ++i) {
                        float av = (&a[i].x)[kk];
                        acc[i][jh * 4 + 0] += av * w.x;
                        acc[i][jh * 4 + 1] += av * w.y;
                        acc[i][jh * 4 + 2] += av * w.z;
                        acc[i][jh * 4 + 3] += av * w.w;
                    }
                }
            }
        }
        __syncthreads();   // drains vmcnt -> next buffer ready
    }

#pragma unroll
    for (int i = 0; i < RM; ++i) {
        int r = row0 + ty + i * 16;
        if (r < M) {
            float dv = dinv[r];
#pragma unroll
            for (int jh = 0; jh < RN / 4; ++jh) {
                float4 v = make_float4(acc[i][jh * 4 + 0] * dv, acc[i][jh * 4 + 1] * dv,
                                       acc[i][jh * 4 + 2] * dv, acc[i][jh * 4 + 3] * dv);
                *(float4*)(out + (size_t)r * C + tx * RN + jh * 4) = v;
            }
        }
    }
}

// ---------------- Aggregation: out[i] = act(dinv[i]*(tmp[i] + sum tmp[src]) + b) ----------------

template <int C, bool RELU>
__global__ __launch_bounds__(256) void agg_kernel(const float* __restrict__ tmp,
                                                  const int* __restrict__ srcs,
                                                  const int* __restrict__ cnt,
                                                  const int* __restrict__ loc,
                                                  const int* __restrict__ base,
                                                  const float* __restrict__ dinv,
                                                  const float* __restrict__ bias,
                                                  float* __restrict__ out, int M) {
    constexpr int TPN = C / 4;        // threads per node (float4 per thread)
    constexpr int NPB = 256 / TPN;    // nodes per block
    const int t = threadIdx.x;
    const int cq = t % TPN;
    const int node = blockIdx.x * NPB + t / TPN;
    if (node >= M) return;

    const float4* tmp4 = (const float4*)tmp;
    float4 acc = tmp4[(size_t)node * TPN + cq];   // self-loop term
    float4 acc2 = make_float4(0.f, 0.f, 0.f, 0.f);
    const int start = loc[node] + base[node >> 8];
    const int n = cnt[node];
    const int* sp = srcs + start;

    const int jn = n & ~3;
    int s0 = 0, s1 = 0, s2 = 0, s3 = 0;
    if (jn > 0) { s0 = sp[0]; s1 = sp[1]; s2 = sp[2]; s3 = sp[3]; }
    for (int j = 0; j < jn; j += 4) {
        float4 v0 = tmp4[(size_t)s0 * TPN + cq];
        float4 v1 = tmp4[(size_t)s1 * TPN + cq];
        float4 v2 = tmp4[(size_t)s2 * TPN + cq];
        float4 v3 = tmp4[(size_t)s3 * TPN + cq];
        if (j + 4 < jn) {
            s0 = sp[j + 4]; s1 = sp[j + 5]; s2 = sp[j + 6]; s3 = sp[j + 7];
        }
        acc.x  += v0.x + v1.x;  acc.y  += v0.y + v1.y;
        acc.z  += v0.z + v1.z;  acc.w  += v0.w + v1.w;
        acc2.x += v2.x + v3.x;  acc2.y += v2.y + v3.y;
        acc2.z += v2.z + v3.z;  acc2.w += v2.w + v3.w;
    }
    for (int j = jn; j < n; ++j) {
        float4 v = tmp4[(size_t)sp[j] * TPN + cq];
        acc.x += v.x; acc.y += v.y; acc.z += v.z; acc.w += v.w;
    }
    acc.x += acc2.x; acc.y += acc2.y; acc.z += acc2.z; acc.w += acc2.w;

    float dv = dinv[node];
    float4 b = *(const float4*)(bias + cq * 4);
    float4 r;
    r.x = acc.x * dv + b.x;
    r.y = acc.y * dv + b.y;
    r.z = acc.z * dv + b.z;
    r.w = acc.w * dv + b.w;
    if (RELU) {
        r.x = fmaxf(r.x, 0.f); r.y = fmaxf(r.y, 0.f);
        r.z = fmaxf(r.z, 0.f); r.w = fmaxf(r.w, 0.f);
    }
    ((float4*)out)[(size_t)node * TPN + cq] = r;
}

// ---------------- launch ----------------

extern "C" void kernel_launch(void* const* d_in, const int* in_sizes, int n_in,
                              void* d_out, int out_size, void* d_ws, size_t ws_size,
                              hipStream_t stream) {
    const float* x  = (const float*)d_in[0];
    const int*   ei = (const int*)d_in[1];
    const float* W1 = (const float*)d_in[2];
    const float* b1 = (const float*)d_in[3];
    const float* W2 = (const float*)d_in[4];
    const float* b2 = (const float*)d_in[5];
    const float* W3 = (const float*)d_in[6];
    const float* b3 = (const float*)d_in[7];
    float* out = (float*)d_out;

    const int M = in_sizes[0] / 256;   // 50000 nodes
    const int E = in_sizes[1] / 2;     // 800000 edges
    const int NB = (M + 255) / 256;

    char* p = (char*)d_ws;
    auto alloc = [&](size_t bytes) {
        char* r = p;
        p += (bytes + 255) & ~(size_t)255;
        return r;
    };
    int*   cnt  = (int*)alloc((size_t)M * 4);
    int*   fill = (int*)alloc((size_t)M * 4);
    int*   loc  = (int*)alloc((size_t)M * 4);
    int*   base = (int*)alloc((size_t)NB * 4);
    float* dinv = (float*)alloc((size_t)M * 4);
    int*   srcs = (int*)alloc((size_t)E * 4);
    float* tmp  = (float*)alloc((size_t)M * 128 * 4);
    float* h    = (float*)alloc((size_t)M * 128 * 4);

    hipMemsetAsync(cnt, 0, (size_t)M * 4, stream);
    hipMemsetAsync(fill, 0, (size_t)M * 4, stream);

    const int* esrc = ei;
    const int* edst = ei + E;

    count_kernel<<<(E + 255) / 256, 256, 0, stream>>>(edst, cnt, E);
    dinv_kernel<<<(M + 255) / 256, 256, 0, stream>>>(cnt, dinv, M);
    scan1_kernel<<<NB, 256, 0, stream>>>(cnt, loc, base, M);
    scan2_kernel<<<1, 256, 0, stream>>>(base, NB);
    place_kernel<<<(E + 255) / 256, 256, 0, stream>>>(esrc, edst, loc, base, fill, srcs, E);

    const int gemm_grid = (M + 63) / 64;   // 782

    // layer 1: x[50000,256] @ W1[256,128] -> relu agg -> h
    gemm_v3<256, 128, 8><<<gemm_grid, 256, 0, stream>>>(x, W1, dinv, tmp, M);
    agg_kernel<128, true><<<(M + 7) / 8, 256, 0, stream>>>(tmp, srcs, cnt, loc, base, dinv, b1, h, M);

    // layer 2: h @ W2[128,128] -> relu agg -> h
    gemm_v3<128, 128, 8><<<gemm_grid, 256, 0, stream>>>(h, W2, dinv, tmp, M);
    agg_kernel<128, true><<<(M + 7) / 8, 256, 0, stream>>>(tmp, srcs, cnt, loc, base, dinv, b2, h, M);

    // layer 3: h @ W3[128,64] -> agg -> out
    gemm_v3<128, 64, 4><<<gemm_grid, 256, 0, stream>>>(h, W3, dinv, tmp, M);
    agg_kernel<64, false><<<(M + 15) / 16, 256, 0, stream>>>(tmp, srcs, cnt, loc, base, dinv, b3, out, M);
}